// Round 5
// baseline (1106.088 us; speedup 1.0000x reference)
//
#include <hip/hip_runtime.h>

// ---------------------------------------------------------------------------
// Dims: E=768 P=256 K=32 V=32 H=128 NE=8  B=16 M=4 T=512
// rows = B*M*T = 32768, sequences = B*M = 64
// ALL inputs are FLOAT32 (reference signature); output is FLOAT32.
// (R1-R3 read them as bf16: NaN -> relu-sanitized zeros -> bit-identical
//  1.6640625 failures; R4's f32 stores exposed the NaN. This round fixes I/O.)
// Internal intermediates: proc/gout bf16, everything else f32.
// ---------------------------------------------------------------------------

__device__ __forceinline__ float bf2f(unsigned short u) {
    return __uint_as_float(((unsigned int)u) << 16);
}
__device__ __forceinline__ unsigned short f2bf(float f) {  // RNE
    unsigned int x = __float_as_uint(f);
    return (unsigned short)((x + 0x7FFFu + ((x >> 16) & 1u)) >> 16);
}
__device__ __forceinline__ float sigm(float x) { return 1.0f / (1.0f + __expf(-x)); }
__device__ __forceinline__ float tanh_fast(float x) {
    x = fminf(fmaxf(x, -15.0f), 15.0f);
    float e = __expf(-2.0f * x);
    return (1.0f - e) / (1.0f + e);
}

// const block layout (floats): wA@0 wB@256 wC@512 | cA,cB,cC@768 |
// wu@800 wA2@1184 wB2@1568 cc@1952  (end 2336)
#define CST_SC   768
#define CST_WU   800
#define CST_WA2  1184
#define CST_WB2  1568
#define CST_CC   1952

__global__ void k_paint(float* out, float val, int nmax) {
    int i = blockIdx.x * blockDim.x + threadIdx.x;
    if (i < nmax) out[i] = val;
}

// ---------------------------------------------------------------------------
// k_prep: all weight fusions.  <<<1, 512>>>
//  wA[p]=Wq[p,:].Wk[0,:]  wB: .Wk[1,:]  wC: .bk          (p<256)
//  cA=bq.Wk0 cB=bq.Wk1 cC=bq.bk
//  wu[g]=Wih[g,0]; wA2[g]=Wih[g,1:].Wv0; wB2[g]=Wih[g,1:].Wv1;
//  cc[g]=bih[g]+Wih[g,1:].bv                              (g<384)
// ---------------------------------------------------------------------------
__global__ void k_prep(const float* __restrict__ Wq,
                       const float* __restrict__ bq,
                       const float* __restrict__ Wk,
                       const float* __restrict__ bk,
                       const float* __restrict__ Wv,
                       const float* __restrict__ bv,
                       const float* __restrict__ Wih,
                       const float* __restrict__ bih,
                       float* __restrict__ cst)
{
    const int t = threadIdx.x;
    if (t < 256) {
        float a = 0.f, b = 0.f, c = 0.f;
        for (int k = 0; k < 32; ++k) {
            float w = Wq[t * 32 + k];
            a = fmaf(w, Wk[k], a);
            b = fmaf(w, Wk[32 + k], b);
            c = fmaf(w, bk[k], c);
        }
        cst[t] = a; cst[256 + t] = b; cst[512 + t] = c;
    }
    if (t == 0) {
        float ca = 0.f, cb = 0.f, cc = 0.f;
        for (int k = 0; k < 32; ++k) {
            float bqk = bq[k];
            ca = fmaf(bqk, Wk[k], ca);
            cb = fmaf(bqk, Wk[32 + k], cb);
            cc = fmaf(bqk, bk[k], cc);
        }
        cst[CST_SC + 0] = ca; cst[CST_SC + 1] = cb; cst[CST_SC + 2] = cc;
    }
    if (t < 384) {
        cst[CST_WU + t] = Wih[t * 33];
        float a2 = 0.f, b2 = 0.f, c2 = bih[t];
        for (int v = 0; v < 32; ++v) {
            float w = Wih[t * 33 + 1 + v];
            a2 = fmaf(w, Wv[v], a2);
            b2 = fmaf(w, Wv[32 + v], b2);
            c2 = fmaf(w, bv[v], c2);
        }
        cst[CST_WA2 + t] = a2; cst[CST_WB2 + t] = b2; cst[CST_CC + t] = c2;
    }
}

// ---------------------------------------------------------------------------
// k_proc: proc = relu(emb @ W_tp + b_tp)  [32768,768]x[768,256] -> bf16
// grid (4, 512), block 256. 64x64 tile, BK=16, 4x4 microtile. f32 inputs.
// ---------------------------------------------------------------------------
__global__ __launch_bounds__(256) void k_proc(
    const float* __restrict__ A,     // [32768,768] f32
    const float* __restrict__ Bw,    // [768,256]  f32
    const float* __restrict__ bias,  // [256] f32
    unsigned short* __restrict__ C)  // [32768,256] bf16
{
    __shared__ float As[64][17];
    __shared__ float Bs[16][64];
    const int t = threadIdx.x;
    const int row0 = blockIdx.y * 64;
    const int col0 = blockIdx.x * 64;
    const int ty = t >> 4, tx = t & 15;
    float acc[4][4] = {};

    for (int k0 = 0; k0 < 768; k0 += 16) {
        {
            const int r = t >> 2, kq = (t & 3) * 4;
            float4 av = *(const float4*)(A + (size_t)(row0 + r) * 768 + k0 + kq);
            As[r][kq + 0] = av.x; As[r][kq + 1] = av.y;
            As[r][kq + 2] = av.z; As[r][kq + 3] = av.w;
        }
        {
            const int kr = t >> 4, cq = (t & 15) * 4;
            float4 bv = *(const float4*)(Bw + (size_t)(k0 + kr) * 256 + col0 + cq);
            Bs[kr][cq + 0] = bv.x; Bs[kr][cq + 1] = bv.y;
            Bs[kr][cq + 2] = bv.z; Bs[kr][cq + 3] = bv.w;
        }
        __syncthreads();
        #pragma unroll
        for (int k = 0; k < 16; ++k) {
            float a[4], b[4];
            #pragma unroll
            for (int i = 0; i < 4; ++i) a[i] = As[ty * 4 + i][k];
            #pragma unroll
            for (int j = 0; j < 4; ++j) b[j] = Bs[k][tx * 4 + j];
            #pragma unroll
            for (int i = 0; i < 4; ++i)
                #pragma unroll
                for (int j = 0; j < 4; ++j)
                    acc[i][j] = fmaf(a[i], b[j], acc[i][j]);
        }
        __syncthreads();
    }
    #pragma unroll
    for (int i = 0; i < 4; ++i) {
        const int r = row0 + ty * 4 + i;
        ushort4 pk;
        pk.x = f2bf(fmaxf(acc[i][0] + bias[col0 + tx * 4 + 0], 0.f));
        pk.y = f2bf(fmaxf(acc[i][1] + bias[col0 + tx * 4 + 1], 0.f));
        pk.z = f2bf(fmaxf(acc[i][2] + bias[col0 + tx * 4 + 2], 0.f));
        pk.w = f2bf(fmaxf(acc[i][3] + bias[col0 + tx * 4 + 3], 0.f));
        *(ushort4*)(C + (size_t)r * 256 + col0 + tx * 4) = pk;
    }
}

// ---------------------------------------------------------------------------
// k_attn: one WAVE per row; rank-1 attention reduced to (wr, ws) per row.
//   dA = proc_row.wA + cA (etc.); score_j = (r_j*dA + s_j*dB + dC)/sqrt(K),
//   mask j==m; wr = sum_j w_j r_j, ws = sum_j w_j s_j.
// ---------------------------------------------------------------------------
__global__ __launch_bounds__(256) void k_attn(
    const unsigned short* __restrict__ proc,  // bf16 internal
    const float* __restrict__ R,              // [16,4,4,512] f32
    const float* __restrict__ S,              // [16,4,4,512] f32
    const float* __restrict__ cst,
    float* __restrict__ wrws)                 // [32768,2] f32
{
    __shared__ float wv_s[768];
    const int tid = threadIdx.x;
    for (int i = tid; i < 768; i += 256) wv_s[i] = cst[i];
    __syncthreads();

    const int lane = tid & 63, wave = tid >> 6;
    const int row = blockIdx.x * 4 + wave;
    const int t = row & 511, m = (row >> 9) & 3, b = row >> 11;
    const int p0 = lane * 4;

    ushort4 u = *(const ushort4*)(proc + (size_t)row * 256 + p0);
    float p0f = bf2f(u.x), p1f = bf2f(u.y), p2f = bf2f(u.z), p3f = bf2f(u.w);
    float dA = 0.f, dB = 0.f, dC = 0.f;
    dA = fmaf(p0f, wv_s[p0 + 0], dA); dB = fmaf(p0f, wv_s[256 + p0 + 0], dB); dC = fmaf(p0f, wv_s[512 + p0 + 0], dC);
    dA = fmaf(p1f, wv_s[p0 + 1], dA); dB = fmaf(p1f, wv_s[256 + p0 + 1], dB); dC = fmaf(p1f, wv_s[512 + p0 + 1], dC);
    dA = fmaf(p2f, wv_s[p0 + 2], dA); dB = fmaf(p2f, wv_s[256 + p0 + 2], dB); dC = fmaf(p2f, wv_s[512 + p0 + 2], dC);
    dA = fmaf(p3f, wv_s[p0 + 3], dA); dB = fmaf(p3f, wv_s[256 + p0 + 3], dB); dC = fmaf(p3f, wv_s[512 + p0 + 3], dC);
    #pragma unroll
    for (int mm = 1; mm < 64; mm <<= 1) {
        dA += __shfl_xor(dA, mm, 64);
        dB += __shfl_xor(dB, mm, 64);
        dC += __shfl_xor(dC, mm, 64);
    }
    if (lane == 0) {
        dA += cst[CST_SC + 0]; dB += cst[CST_SC + 1]; dC += cst[CST_SC + 2];
        const float scale = 0.17677669529663687f;  // 1/sqrt(32)
        float rr[4], ss[4], sc[4], mx = -1e30f;
        #pragma unroll
        for (int j = 0; j < 4; ++j) {
            const size_t idx = ((size_t)(b * 16 + m * 4 + j)) * 512 + t;
            rr[j] = R[idx]; ss[j] = S[idx];
            float v = (rr[j] * dA + ss[j] * dB + dC) * scale;
            if (j == m) v = -1e9f;
            sc[j] = v; mx = fmaxf(mx, v);
        }
        float w[4], se = 0.f;
        #pragma unroll
        for (int j = 0; j < 4; ++j) { w[j] = __expf(sc[j] - mx); se += w[j]; }
        const float inv = 1.0f / se;
        float wr = 0.f, wss = 0.f;
        #pragma unroll
        for (int j = 0; j < 4; ++j) { wr += w[j] * rr[j]; wss += w[j] * ss[j]; }
        float2 o; o.x = wr * inv; o.y = wss * inv;
        ((float2*)wrws)[row] = o;
    }
}

// ---------------------------------------------------------------------------
// k_gru: 64 blocks x 384 threads (one per gate-row g).
// gi[g] = cc[g] + U_t*wu[g] + wr_t*wA2[g] + ws_t*wB2[g]   (3 fmas)
// gh[g] = bhh[g] + W_hh[g,:].h   (W row in 128 VGPRs, f32)
// ---------------------------------------------------------------------------
__global__ __launch_bounds__(384) void k_gru(
    const float* __restrict__ wrws,
    const float* __restrict__ U,       // [32768] f32
    const float* __restrict__ Whh,     // [384,128] f32
    const float* __restrict__ bhh,     // [384] f32
    const float* __restrict__ cst,
    unsigned short* __restrict__ gout) // [32768,128] bf16
{
    __shared__ float h_s[128];
    __shared__ float sgi[384];
    __shared__ float sgh[384];
    __shared__ float u_s[512];
    __shared__ float wr_s[512];
    __shared__ float ws_s[512];
    const int g = threadIdx.x;
    const int n = blockIdx.x;

    float wf[128];
    const float4* wp = (const float4*)(Whh + (size_t)g * 128);
    #pragma unroll
    for (int k = 0; k < 32; ++k) {
        float4 w4 = wp[k];
        wf[4 * k + 0] = w4.x; wf[4 * k + 1] = w4.y;
        wf[4 * k + 2] = w4.z; wf[4 * k + 3] = w4.w;
    }
    const float bg   = bhh[g];
    const float wu_g = cst[CST_WU + g];
    const float wa_g = cst[CST_WA2 + g];
    const float wb_g = cst[CST_WB2 + g];
    const float cc_g = cst[CST_CC + g];

    for (int i = g; i < 512; i += 384) {
        u_s[i] = U[n * 512 + i];
        float2 w2 = ((const float2*)wrws)[n * 512 + i];
        wr_s[i] = w2.x; ws_s[i] = w2.y;
    }
    if (g < 128) h_s[g] = 0.f;
    __syncthreads();

    for (int t = 0; t < 512; ++t) {
        float gi = fmaf(u_s[t], wu_g, fmaf(wr_s[t], wa_g, fmaf(ws_s[t], wb_g, cc_g)));
        float c0 = bg, c1 = 0.f, c2 = 0.f, c3 = 0.f;
        #pragma unroll
        for (int q = 0; q < 32; ++q) {
            float4 h4 = ((const float4*)h_s)[q];
            c0 = fmaf(wf[4 * q + 0], h4.x, c0);
            c1 = fmaf(wf[4 * q + 1], h4.y, c1);
            c2 = fmaf(wf[4 * q + 2], h4.z, c2);
            c3 = fmaf(wf[4 * q + 3], h4.w, c3);
        }
        sgi[g] = gi;
        sgh[g] = (c0 + c1) + (c2 + c3);
        __syncthreads();
        if (g < 128) {
            float r  = sigm(sgi[g] + sgh[g]);
            float z  = sigm(sgi[g + 128] + sgh[g + 128]);
            float nn = tanh_fast(sgi[g + 256] + r * sgh[g + 256]);
            float hn = (1.f - z) * nn + z * h_s[g];
            h_s[g] = hn;
            gout[((size_t)n * 512 + t) * 128 + g] = f2bf(hn);
        }
        __syncthreads();
    }
}

// ---------------------------------------------------------------------------
// k_hid: hidden = relu([proc|gout]@W1 + b1) in LDS, logits = hidden@W2+b2.
// f32 weights, f32 OUTPUT. 64 rows/block, grid 512, block 256.
// ---------------------------------------------------------------------------
__global__ __launch_bounds__(256) void k_hid(
    const unsigned short* __restrict__ proc,  // bf16 internal
    const unsigned short* __restrict__ gout,  // bf16 internal
    const float* __restrict__ W1,   // [384,192] f32
    const float* __restrict__ b1,   // [192] f32
    const float* __restrict__ W2,   // [192,8] f32
    const float* __restrict__ b2,   // [8] f32
    float* __restrict__ out)        // [32768,8] f32
{
    __shared__ float smem[14088];
    float* As  = smem;              // [64][17]  (K-loop)
    float* Bs  = smem + 1088;       // [16][192] (K-loop)
    float* Hs  = smem;              // [64][196] (epilogue; reuses As/Bs)
    float* W2s = smem + 12544;      // 1536
    float* b2s = smem + 14080;      // 8
    const int tid = threadIdx.x;
    const int row0 = blockIdx.x * 64;
    for (int i = tid; i < 1536; i += 256) W2s[i] = W2[i];
    if (tid < 8) b2s[tid] = b2[tid];
    const int ty = tid >> 4, tx = tid & 15;
    const int ar = tid >> 2, akq = (tid & 3) * 4;
    const int bkr = tid >> 4, bc0 = (tid & 15) * 12;
    float acc[4][12] = {};

    for (int k0 = 0; k0 < 384; k0 += 16) {
        {
            const int kk = k0 + akq;
            ushort4 u;
            if (kk < 256) u = *(const ushort4*)(proc + (size_t)(row0 + ar) * 256 + kk);
            else          u = *(const ushort4*)(gout + (size_t)(row0 + ar) * 128 + (kk - 256));
            As[ar * 17 + akq + 0] = bf2f(u.x); As[ar * 17 + akq + 1] = bf2f(u.y);
            As[ar * 17 + akq + 2] = bf2f(u.z); As[ar * 17 + akq + 3] = bf2f(u.w);
        }
        {
            const float* wsrc = W1 + (size_t)(k0 + bkr) * 192 + bc0;
            #pragma unroll
            for (int q = 0; q < 3; ++q) {
                float4 w4 = *(const float4*)(wsrc + 4 * q);
                Bs[bkr * 192 + bc0 + 4 * q + 0] = w4.x;
                Bs[bkr * 192 + bc0 + 4 * q + 1] = w4.y;
                Bs[bkr * 192 + bc0 + 4 * q + 2] = w4.z;
                Bs[bkr * 192 + bc0 + 4 * q + 3] = w4.w;
            }
        }
        __syncthreads();
        #pragma unroll
        for (int k = 0; k < 16; ++k) {
            float a[4], bb[12];
            #pragma unroll
            for (int i = 0; i < 4; ++i) a[i] = As[(ty * 4 + i) * 17 + k];
            #pragma unroll
            for (int j = 0; j < 12; ++j) bb[j] = Bs[k * 192 + tx * 12 + j];
            #pragma unroll
            for (int i = 0; i < 4; ++i)
                #pragma unroll
                for (int j = 0; j < 12; ++j)
                    acc[i][j] = fmaf(a[i], bb[j], acc[i][j]);
        }
        __syncthreads();
    }
    #pragma unroll
    for (int i = 0; i < 4; ++i)
        #pragma unroll
        for (int j = 0; j < 12; ++j) {
            const int c = tx * 12 + j;
            Hs[(ty * 4 + i) * 196 + c] = fmaxf(acc[i][j] + b1[c], 0.f);
        }
    __syncthreads();
    const int r = tid >> 2, qq = tid & 3;
    const int e0 = 2 * qq, e1 = 2 * qq + 1;
    float s0 = b2s[e0], s1 = b2s[e1];
    for (int c = 0; c < 192; ++c) {
        float h = Hs[r * 196 + c];
        s0 = fmaf(h, W2s[c * 8 + e0], s0);
        s1 = fmaf(h, W2s[c * 8 + e1], s1);
    }
    out[(size_t)(row0 + r) * 8 + e0] = s0;
    out[(size_t)(row0 + r) * 8 + e1] = s1;
}

// ---------------------------------------------------------------------------
extern "C" void kernel_launch(void* const* d_in, const int* in_sizes, int n_in,
                              void* d_out, int out_size, void* d_ws, size_t ws_size,
                              hipStream_t stream) {
    const float* emb  = (const float*)d_in[0];
    const float* U    = (const float*)d_in[1];
    const float* R    = (const float*)d_in[2];
    const float* S    = (const float*)d_in[3];
    const float* W_tp = (const float*)d_in[4];
    const float* b_tp = (const float*)d_in[5];
    const float* W_q  = (const float*)d_in[6];
    const float* b_q  = (const float*)d_in[7];
    const float* W_k  = (const float*)d_in[8];
    const float* b_k  = (const float*)d_in[9];
    const float* W_v  = (const float*)d_in[10];
    const float* b_v  = (const float*)d_in[11];
    const float* W_ih = (const float*)d_in[12];
    const float* W_hh = (const float*)d_in[13];
    const float* b_ih = (const float*)d_in[14];
    const float* b_hh = (const float*)d_in[15];
    const float* W1   = (const float*)d_in[16];
    const float* b1   = (const float*)d_in[17];
    const float* W2   = (const float*)d_in[18];
    const float* b2   = (const float*)d_in[19];

    float* outp = (float*)d_out;

    // ws layout (bytes) — 25.4 MB, proven to fit (R3 guard never fired):
    //   proc  bf16 [32768,256] @ 0            16,777,216
    //   wrws  f32  [32768,2]   @ 16,777,216      262,144
    //   gout  bf16 [32768,128] @ 17,039,360    8,388,608
    //   cst   f32  [2336]      @ 25,427,968        9,344
    const size_t NEEDED = 25444352u;
    if (ws_size < NEEDED) {
        k_paint<<<(out_size + 255) / 256, 256, 0, stream>>>(outp, 3.0f, out_size);
        return;
    }

    char* ws = (char*)d_ws;
    unsigned short* proc = (unsigned short*)(ws);
    float*          wrws = (float*)(ws + 16777216u);
    unsigned short* gout = (unsigned short*)(ws + 17039360u);
    float*          cst  = (float*)(ws + 25427968u);

    k_prep<<<1, 512, 0, stream>>>(W_q, b_q, W_k, b_k, W_v, b_v, W_ih, b_ih, cst);
    k_proc<<<dim3(4, 512), 256, 0, stream>>>(emb, W_tp, b_tp, proc);
    k_attn<<<8192, 256, 0, stream>>>(proc, R, S, cst, wrws);
    k_gru <<<64, 384, 0, stream>>>(wrws, U, W_hh, b_hh, cst, gout);
    k_hid <<<512, 256, 0, stream>>>(proc, gout, W1, b1, W2, b2, outp);
}

// Round 6
// 861.256 us; speedup vs baseline: 1.2843x; 1.2843x over previous
//
#include <hip/hip_runtime.h>

// ---------------------------------------------------------------------------
// Dims: E=768 P=256 K=32 V=32 H=128 NE=8  B=16 M=4 T=512
// rows = 32768, sequences = 64.  All inputs f32; output f32.
// R5 counters: k_gru 662us (wf[128] spilled @ VGPR=120 -> L2 re-read 192KB/step
// = ~3400 cyc/step, matches 3105 measured). Fix: 2 thr/gate-row, 64 VGPR wts.
// k_proc ~300us scalar VALU -> bf16 MFMA 16x16x32.
// ---------------------------------------------------------------------------

typedef __attribute__((ext_vector_type(8))) short short8;
typedef __attribute__((ext_vector_type(4))) float f32x4;

__device__ __forceinline__ float bf2f(unsigned short u) {
    return __uint_as_float(((unsigned int)u) << 16);
}
__device__ __forceinline__ unsigned short f2bf(float f) {  // RNE
    unsigned int x = __float_as_uint(f);
    return (unsigned short)((x + 0x7FFFu + ((x >> 16) & 1u)) >> 16);
}
__device__ __forceinline__ float sigm(float x) { return 1.0f / (1.0f + __expf(-x)); }
__device__ __forceinline__ float tanh_fast(float x) {
    x = fminf(fmaxf(x, -15.0f), 15.0f);
    float e = __expf(-2.0f * x);
    return (1.0f - e) / (1.0f + e);
}

// const block layout (floats): wA@0 wB@256 wC@512 | cA,cB,cC@768 |
// wu@800 wA2@1184 wB2@1568 cc@1952  (end 2336)
#define CST_SC   768
#define CST_WU   800
#define CST_WA2  1184
#define CST_WB2  1568
#define CST_CC   1952

__global__ void k_paint(float* out, float val, int nmax) {
    int i = blockIdx.x * blockDim.x + threadIdx.x;
    if (i < nmax) out[i] = val;
}

// ---------------------------------------------------------------------------
// k_prep: weight fusions.  <<<1, 512>>>
// ---------------------------------------------------------------------------
__global__ void k_prep(const float* __restrict__ Wq,
                       const float* __restrict__ bq,
                       const float* __restrict__ Wk,
                       const float* __restrict__ bk,
                       const float* __restrict__ Wv,
                       const float* __restrict__ bv,
                       const float* __restrict__ Wih,
                       const float* __restrict__ bih,
                       float* __restrict__ cst)
{
    const int t = threadIdx.x;
    if (t < 256) {
        float a = 0.f, b = 0.f, c = 0.f;
        for (int k = 0; k < 32; ++k) {
            float w = Wq[t * 32 + k];
            a = fmaf(w, Wk[k], a);
            b = fmaf(w, Wk[32 + k], b);
            c = fmaf(w, bk[k], c);
        }
        cst[t] = a; cst[256 + t] = b; cst[512 + t] = c;
    }
    if (t == 0) {
        float ca = 0.f, cb = 0.f, cc = 0.f;
        for (int k = 0; k < 32; ++k) {
            float bqk = bq[k];
            ca = fmaf(bqk, Wk[k], ca);
            cb = fmaf(bqk, Wk[32 + k], cb);
            cc = fmaf(bqk, bk[k], cc);
        }
        cst[CST_SC + 0] = ca; cst[CST_SC + 1] = cb; cst[CST_SC + 2] = cc;
    }
    if (t < 384) {
        cst[CST_WU + t] = Wih[t * 33];
        float a2 = 0.f, b2 = 0.f, c2 = bih[t];
        for (int v = 0; v < 32; ++v) {
            float w = Wih[t * 33 + 1 + v];
            a2 = fmaf(w, Wv[v], a2);
            b2 = fmaf(w, Wv[32 + v], b2);
            c2 = fmaf(w, bv[v], c2);
        }
        cst[CST_WA2 + t] = a2; cst[CST_WB2 + t] = b2; cst[CST_CC + t] = c2;
    }
}

// ---------------------------------------------------------------------------
// k_proc: proc = relu(emb @ W_tp + b_tp)  [32768,768]x[768,256] -> bf16
// MFMA 16x16x32 bf16. Block 256 (4 waves), tile 64x64, BK=32, grid (4,512).
// LDS tiles padded to stride 40 (bank-conflict-free-ish). f32->bf16 in staging.
// ---------------------------------------------------------------------------
__global__ __launch_bounds__(256) void k_proc(
    const float* __restrict__ A,     // [32768,768] f32
    const float* __restrict__ Bw,    // [768,256]  f32
    const float* __restrict__ bias,  // [256] f32
    unsigned short* __restrict__ C)  // [32768,256] bf16
{
    __shared__ unsigned short A_s[64 * 40];  // [row][k] stride 40
    __shared__ unsigned short B_s[64 * 40];  // [col][k] stride 40 (transposed)
    const int t = threadIdx.x;
    const int row0 = blockIdx.y * 64;
    const int col0 = blockIdx.x * 64;
    const int lane = t & 63, wave = t >> 6;
    const int wr = wave >> 1, wc = wave & 1;      // 2x2 wave grid of 32x32
    const int quad = lane >> 4, l16 = lane & 15;

    f32x4 acc[2][2] = {};

    for (int k0 = 0; k0 < 768; k0 += 32) {
        {   // A tile: 64 rows x 32 k
            const int r = t >> 2, kq = (t & 3) * 8;
            const float* src = A + (size_t)(row0 + r) * 768 + k0 + kq;
            float4 v0 = *(const float4*)(src);
            float4 v1 = *(const float4*)(src + 4);
            short8 s;
            s[0] = f2bf(v0.x); s[1] = f2bf(v0.y); s[2] = f2bf(v0.z); s[3] = f2bf(v0.w);
            s[4] = f2bf(v1.x); s[5] = f2bf(v1.y); s[6] = f2bf(v1.z); s[7] = f2bf(v1.w);
            *(short8*)(A_s + r * 40 + kq) = s;
        }
        {   // B tile: 32 k x 64 cols, transposed into [col][k]
            const int k = t >> 3, nq = (t & 7) * 8;
            const float* src = Bw + (size_t)(k0 + k) * 256 + col0 + nq;
            float4 v0 = *(const float4*)(src);
            float4 v1 = *(const float4*)(src + 4);
            B_s[(nq + 0) * 40 + k] = f2bf(v0.x);
            B_s[(nq + 1) * 40 + k] = f2bf(v0.y);
            B_s[(nq + 2) * 40 + k] = f2bf(v0.z);
            B_s[(nq + 3) * 40 + k] = f2bf(v0.w);
            B_s[(nq + 4) * 40 + k] = f2bf(v1.x);
            B_s[(nq + 5) * 40 + k] = f2bf(v1.y);
            B_s[(nq + 6) * 40 + k] = f2bf(v1.z);
            B_s[(nq + 7) * 40 + k] = f2bf(v1.w);
        }
        __syncthreads();
        // fragments: A[m=l16][k=quad*8+j], B[k=quad*8+j][n=l16]
        short8 af[2], bf[2];
        #pragma unroll
        for (int im = 0; im < 2; ++im)
            af[im] = *(const short8*)(A_s + (wr * 32 + im * 16 + l16) * 40 + quad * 8);
        #pragma unroll
        for (int in = 0; in < 2; ++in)
            bf[in] = *(const short8*)(B_s + (wc * 32 + in * 16 + l16) * 40 + quad * 8);
        #pragma unroll
        for (int im = 0; im < 2; ++im)
            #pragma unroll
            for (int in = 0; in < 2; ++in)
                acc[im][in] = __builtin_amdgcn_mfma_f32_16x16x32_bf16(
                    af[im], bf[in], acc[im][in], 0, 0, 0);
        __syncthreads();
    }
    // epilogue: C/D layout col=l16, row=quad*4+reg
    float bias_v[2];
    #pragma unroll
    for (int in = 0; in < 2; ++in) bias_v[in] = bias[col0 + wc * 32 + in * 16 + l16];
    #pragma unroll
    for (int im = 0; im < 2; ++im)
        #pragma unroll
        for (int in = 0; in < 2; ++in) {
            const int c_g = col0 + wc * 32 + in * 16 + l16;
            #pragma unroll
            for (int reg = 0; reg < 4; ++reg) {
                const int r_g = row0 + wr * 32 + im * 16 + quad * 4 + reg;
                float v = fmaxf(acc[im][in][reg] + bias_v[in], 0.f);
                C[(size_t)r_g * 256 + c_g] = f2bf(v);
            }
        }
}

// ---------------------------------------------------------------------------
// k_attn: one WAVE per row; rank-1 attention reduced to (wr, ws) per row.
// ---------------------------------------------------------------------------
__global__ __launch_bounds__(256) void k_attn(
    const unsigned short* __restrict__ proc,  // bf16 internal
    const float* __restrict__ R,              // [16,4,4,512] f32
    const float* __restrict__ S,
    const float* __restrict__ cst,
    float* __restrict__ wrws)                 // [32768,2] f32
{
    __shared__ float wv_s[768];
    const int tid = threadIdx.x;
    for (int i = tid; i < 768; i += 256) wv_s[i] = cst[i];
    __syncthreads();

    const int lane = tid & 63, wave = tid >> 6;
    const int row = blockIdx.x * 4 + wave;
    const int t = row & 511, m = (row >> 9) & 3, b = row >> 11;
    const int p0 = lane * 4;

    ushort4 u = *(const ushort4*)(proc + (size_t)row * 256 + p0);
    float p0f = bf2f(u.x), p1f = bf2f(u.y), p2f = bf2f(u.z), p3f = bf2f(u.w);
    float dA = 0.f, dB = 0.f, dC = 0.f;
    dA = fmaf(p0f, wv_s[p0 + 0], dA); dB = fmaf(p0f, wv_s[256 + p0 + 0], dB); dC = fmaf(p0f, wv_s[512 + p0 + 0], dC);
    dA = fmaf(p1f, wv_s[p0 + 1], dA); dB = fmaf(p1f, wv_s[256 + p0 + 1], dB); dC = fmaf(p1f, wv_s[512 + p0 + 1], dC);
    dA = fmaf(p2f, wv_s[p0 + 2], dA); dB = fmaf(p2f, wv_s[256 + p0 + 2], dB); dC = fmaf(p2f, wv_s[512 + p0 + 2], dC);
    dA = fmaf(p3f, wv_s[p0 + 3], dA); dB = fmaf(p3f, wv_s[256 + p0 + 3], dB); dC = fmaf(p3f, wv_s[512 + p0 + 3], dC);
    #pragma unroll
    for (int mm = 1; mm < 64; mm <<= 1) {
        dA += __shfl_xor(dA, mm, 64);
        dB += __shfl_xor(dB, mm, 64);
        dC += __shfl_xor(dC, mm, 64);
    }
    if (lane == 0) {
        dA += cst[CST_SC + 0]; dB += cst[CST_SC + 1]; dC += cst[CST_SC + 2];
        const float scale = 0.17677669529663687f;  // 1/sqrt(32)
        float rr[4], ss[4], sc[4], mx = -1e30f;
        #pragma unroll
        for (int j = 0; j < 4; ++j) {
            const size_t idx = ((size_t)(b * 16 + m * 4 + j)) * 512 + t;
            rr[j] = R[idx]; ss[j] = S[idx];
            float v = (rr[j] * dA + ss[j] * dB + dC) * scale;
            if (j == m) v = -1e9f;
            sc[j] = v; mx = fmaxf(mx, v);
        }
        float w[4], se = 0.f;
        #pragma unroll
        for (int j = 0; j < 4; ++j) { w[j] = __expf(sc[j] - mx); se += w[j]; }
        const float inv = 1.0f / se;
        float wr = 0.f, wss = 0.f;
        #pragma unroll
        for (int j = 0; j < 4; ++j) { wr += w[j] * rr[j]; wss += w[j] * ss[j]; }
        float2 o; o.x = wr * inv; o.y = wss * inv;
        ((float2*)wrws)[row] = o;
    }
}

// ---------------------------------------------------------------------------
// k_gru: 64 blocks x 768 threads. TWO threads per gate-row g (half=tid&1),
// each holds 64 f32 weights in VGPRs (NO SPILL; R5's wf[128] spilled at
// VGPR=120 and cost 3100 cyc/step of L2 traffic). Pair-sum via shfl_xor(1).
// gi[g] = cc[g] + U_t*wu[g] + wr_t*wA2[g] + ws_t*wB2[g]
// ---------------------------------------------------------------------------
__global__ __launch_bounds__(768) void k_gru(
    const float* __restrict__ wrws,
    const float* __restrict__ U,       // [32768] f32
    const float* __restrict__ Whh,     // [384,128] f32
    const float* __restrict__ bhh,     // [384] f32
    const float* __restrict__ cst,
    unsigned short* __restrict__ gout) // [32768,128] bf16
{
    __shared__ float h_s[128];
    __shared__ float sgi[384];
    __shared__ float sgh[384];
    __shared__ float u_s[512];
    __shared__ float wr_s[512];
    __shared__ float ws_s[512];
    const int tid = threadIdx.x;
    const int g = tid >> 1, half = tid & 1;
    const int n = blockIdx.x;

    float wf[64];   // 64 VGPRs: half of W_hh[g,:]
    const float4* wp = (const float4*)(Whh + (size_t)g * 128 + half * 64);
    #pragma unroll
    for (int k = 0; k < 16; ++k) {
        float4 w4 = wp[k];
        wf[4 * k + 0] = w4.x; wf[4 * k + 1] = w4.y;
        wf[4 * k + 2] = w4.z; wf[4 * k + 3] = w4.w;
    }
    const float bg   = half ? 0.f : bhh[g];
    const float wu_g = cst[CST_WU + g];
    const float wa_g = cst[CST_WA2 + g];
    const float wb_g = cst[CST_WB2 + g];
    const float cc_g = cst[CST_CC + g];

    if (tid < 512) {
        u_s[tid] = U[n * 512 + tid];
        float2 w2 = ((const float2*)wrws)[n * 512 + tid];
        wr_s[tid] = w2.x; ws_s[tid] = w2.y;
    }
    if (tid < 128) h_s[tid] = 0.f;
    __syncthreads();

    const float* hb = h_s + half * 64;
    for (int t = 0; t < 512; ++t) {
        float c0 = bg, c1 = 0.f, c2 = 0.f, c3 = 0.f;
        #pragma unroll
        for (int q = 0; q < 16; ++q) {
            float4 h4 = ((const float4*)hb)[q];
            c0 = fmaf(wf[4 * q + 0], h4.x, c0);
            c1 = fmaf(wf[4 * q + 1], h4.y, c1);
            c2 = fmaf(wf[4 * q + 2], h4.z, c2);
            c3 = fmaf(wf[4 * q + 3], h4.w, c3);
        }
        float sum = (c0 + c1) + (c2 + c3);
        sum += __shfl_xor(sum, 1, 64);          // pair-combine halves
        if (half) {
            sgh[g] = sum;
        } else {
            sgi[g] = fmaf(u_s[t], wu_g, fmaf(wr_s[t], wa_g, fmaf(ws_s[t], wb_g, cc_g)));
        }
        __syncthreads();
        if (tid < 128) {
            float r  = sigm(sgi[tid] + sgh[tid]);
            float z  = sigm(sgi[tid + 128] + sgh[tid + 128]);
            float nn = tanh_fast(sgi[tid + 256] + r * sgh[tid + 256]);
            float hn = (1.f - z) * nn + z * h_s[tid];
            h_s[tid] = hn;
            gout[((size_t)n * 512 + t) * 128 + tid] = f2bf(hn);
        }
        __syncthreads();
    }
}

// ---------------------------------------------------------------------------
// k_hid: hidden = relu([proc|gout]@W1 + b1) in LDS, logits = hidden@W2+b2.
// f32 weights, f32 output. 64 rows/block, grid 512, block 256.
// ---------------------------------------------------------------------------
__global__ __launch_bounds__(256) void k_hid(
    const unsigned short* __restrict__ proc,  // bf16 internal
    const unsigned short* __restrict__ gout,  // bf16 internal
    const float* __restrict__ W1,   // [384,192] f32
    const float* __restrict__ b1,   // [192] f32
    const float* __restrict__ W2,   // [192,8] f32
    const float* __restrict__ b2,   // [8] f32
    float* __restrict__ out)        // [32768,8] f32
{
    __shared__ float smem[14088];
    float* As  = smem;              // [64][17]  (K-loop)
    float* Bs  = smem + 1088;       // [16][192] (K-loop)
    float* Hs  = smem;              // [64][196] (epilogue; reuses As/Bs)
    float* W2s = smem + 12544;      // 1536
    float* b2s = smem + 14080;      // 8
    const int tid = threadIdx.x;
    const int row0 = blockIdx.x * 64;
    for (int i = tid; i < 1536; i += 256) W2s[i] = W2[i];
    if (tid < 8) b2s[tid] = b2[tid];
    const int ty = tid >> 4, tx = tid & 15;
    const int ar = tid >> 2, akq = (tid & 3) * 4;
    const int bkr = tid >> 4, bc0 = (tid & 15) * 12;
    float acc[4][12] = {};

    for (int k0 = 0; k0 < 384; k0 += 16) {
        {
            const int kk = k0 + akq;
            ushort4 u;
            if (kk < 256) u = *(const ushort4*)(proc + (size_t)(row0 + ar) * 256 + kk);
            else          u = *(const ushort4*)(gout + (size_t)(row0 + ar) * 128 + (kk - 256));
            As[ar * 17 + akq + 0] = bf2f(u.x); As[ar * 17 + akq + 1] = bf2f(u.y);
            As[ar * 17 + akq + 2] = bf2f(u.z); As[ar * 17 + akq + 3] = bf2f(u.w);
        }
        {
            const float* wsrc = W1 + (size_t)(k0 + bkr) * 192 + bc0;
            #pragma unroll
            for (int q = 0; q < 3; ++q) {
                float4 w4 = *(const float4*)(wsrc + 4 * q);
                Bs[bkr * 192 + bc0 + 4 * q + 0] = w4.x;
                Bs[bkr * 192 + bc0 + 4 * q + 1] = w4.y;
                Bs[bkr * 192 + bc0 + 4 * q + 2] = w4.z;
                Bs[bkr * 192 + bc0 + 4 * q + 3] = w4.w;
            }
        }
        __syncthreads();
        #pragma unroll
        for (int k = 0; k < 16; ++k) {
            float a[4], bb[12];
            #pragma unroll
            for (int i = 0; i < 4; ++i) a[i] = As[(ty * 4 + i) * 17 + k];
            #pragma unroll
            for (int j = 0; j < 12; ++j) bb[j] = Bs[k * 192 + tx * 12 + j];
            #pragma unroll
            for (int i = 0; i < 4; ++i)
                #pragma unroll
                for (int j = 0; j < 12; ++j)
                    acc[i][j] = fmaf(a[i], bb[j], acc[i][j]);
        }
        __syncthreads();
    }
    #pragma unroll
    for (int i = 0; i < 4; ++i)
        #pragma unroll
        for (int j = 0; j < 12; ++j) {
            const int c = tx * 12 + j;
            Hs[(ty * 4 + i) * 196 + c] = fmaxf(acc[i][j] + b1[c], 0.f);
        }
    __syncthreads();
    const int r = tid >> 2, qq = tid & 3;
    const int e0 = 2 * qq, e1 = 2 * qq + 1;
    float s0 = b2s[e0], s1 = b2s[e1];
    for (int c = 0; c < 192; ++c) {
        float h = Hs[r * 196 + c];
        s0 = fmaf(h, W2s[c * 8 + e0], s0);
        s1 = fmaf(h, W2s[c * 8 + e1], s1);
    }
    out[(size_t)(row0 + r) * 8 + e0] = s0;
    out[(size_t)(row0 + r) * 8 + e1] = s1;
}

// ---------------------------------------------------------------------------
extern "C" void kernel_launch(void* const* d_in, const int* in_sizes, int n_in,
                              void* d_out, int out_size, void* d_ws, size_t ws_size,
                              hipStream_t stream) {
    const float* emb  = (const float*)d_in[0];
    const float* U    = (const float*)d_in[1];
    const float* R    = (const float*)d_in[2];
    const float* S    = (const float*)d_in[3];
    const float* W_tp = (const float*)d_in[4];
    const float* b_tp = (const float*)d_in[5];
    const float* W_q  = (const float*)d_in[6];
    const float* b_q  = (const float*)d_in[7];
    const float* W_k  = (const float*)d_in[8];
    const float* b_k  = (const float*)d_in[9];
    const float* W_v  = (const float*)d_in[10];
    const float* b_v  = (const float*)d_in[11];
    const float* W_ih = (const float*)d_in[12];
    const float* W_hh = (const float*)d_in[13];
    const float* b_ih = (const float*)d_in[14];
    const float* b_hh = (const float*)d_in[15];
    const float* W1   = (const float*)d_in[16];
    const float* b1   = (const float*)d_in[17];
    const float* W2   = (const float*)d_in[18];
    const float* b2   = (const float*)d_in[19];

    float* outp = (float*)d_out;

    // ws layout (bytes) — 25.4 MB (verified fits):
    //   proc  bf16 [32768,256] @ 0            16,777,216
    //   wrws  f32  [32768,2]   @ 16,777,216      262,144
    //   gout  bf16 [32768,128] @ 17,039,360    8,388,608
    //   cst   f32  [2336]      @ 25,427,968        9,344
    const size_t NEEDED = 25444352u;
    if (ws_size < NEEDED) {
        k_paint<<<(out_size + 255) / 256, 256, 0, stream>>>(outp, 3.0f, out_size);
        return;
    }

    char* ws = (char*)d_ws;
    unsigned short* proc = (unsigned short*)(ws);
    float*          wrws = (float*)(ws + 16777216u);
    unsigned short* gout = (unsigned short*)(ws + 17039360u);
    float*          cst  = (float*)(ws + 25427968u);

    k_prep<<<1, 512, 0, stream>>>(W_q, b_q, W_k, b_k, W_v, b_v, W_ih, b_ih, cst);
    k_proc<<<dim3(4, 512), 256, 0, stream>>>(emb, W_tp, b_tp, proc);
    k_attn<<<8192, 256, 0, stream>>>(proc, R, S, cst, wrws);
    k_gru <<<64, 768, 0, stream>>>(wrws, U, W_hh, b_hh, cst, gout);
    k_hid <<<512, 256, 0, stream>>>(proc, gout, W1, b1, W2, b2, outp);
}